// Round 6
// baseline (136.732 us; speedup 1.0000x reference)
//
#include <hip/hip_runtime.h>

// Problem constants (match reference): B=16, N=1024, D2H=1024, U=512
#define BB 16
#define NN 1024
#define DD 1024
#define UU 512

// native clang vector type — accepted by __builtin_nontemporal_{load,store}
typedef float f4 __attribute__((ext_vector_type(4)));

// ---------------------------------------------------------------------------
// Kernel A (17 blocks x 1024): deterministic, no atomics, no memset.
// blocks 0..15: v[m*DD + d] = sum_u W[u,d] * w_out[u]  (m=0: W_h, m=1: W_m)
// block 16: C = (b_h+b_m)·w_out + b_out
// ---------------------------------------------------------------------------
__global__ __launch_bounds__(1024) void prep_kernel(
    const float* __restrict__ W_h, const float* __restrict__ W_m,
    const float* __restrict__ b_h, const float* __restrict__ b_m,
    const float* __restrict__ w_out, const float* __restrict__ b_out,
    float* __restrict__ v, float* __restrict__ Cc) {
    const int t = threadIdx.x;
    const int blk = blockIdx.x;
    if (blk < 16) {
        __shared__ float red[8][128];
        const int m = blk >> 3;              // 0 -> W_h, 1 -> W_m
        const int d0 = (blk & 7) * 128;      // d-chunk
        const float* W = m ? W_m : W_h;
        const int dl = t & 127;              // d within chunk
        const int p = t >> 7;                // u-chunk 0..7 (64 u each)
        const float* Wp = W + (size_t)(p * 64) * DD + d0 + dl;
        float acc = 0.f;
        #pragma unroll
        for (int k = 0; k < 64; ++k)
            acc += __builtin_nontemporal_load(Wp + (size_t)k * DD) * w_out[p * 64 + k];
        red[p][dl] = acc;
        __syncthreads();
        if (t < 128) {
            float s = 0.f;
            #pragma unroll
            for (int q = 0; q < 8; ++q) s += red[q][t];
            v[m * DD + d0 + t] = s;
        }
    } else {
        __shared__ float r2[512];
        float acc = 0.f;
        if (t < UU) acc = (b_h[t] + b_m[t]) * w_out[t];
        if (t < 512) r2[t] = acc;
        __syncthreads();
        for (int s = 256; s > 0; s >>= 1) {
            if (t < s) r2[t] += r2[t + s];
            __syncthreads();
        }
        if (t == 0) *Cc = r2[0] + b_out[0];
    }
}

// ---------------------------------------------------------------------------
// Kernel B: sH[row] = x[row]·v_h + C ; sM[row] = x[row]·v_m   (row = b*N+n)
// One wave per row, 4 waves/block. x is streamed nontemporally (zero reuse);
// v (8 KB) stays cache-hot.
// ---------------------------------------------------------------------------
__global__ __launch_bounds__(256) void row_dots_kernel(
    const float* __restrict__ x, const float* __restrict__ v,
    const float* __restrict__ Cc,
    float* __restrict__ sH, float* __restrict__ sM) {
    const int t = threadIdx.x;
    const int wave = t >> 6, lane = t & 63;
    const int row = blockIdx.x * 4 + wave;           // [0, B*N)
    const f4* xr = (const f4*)(x + (size_t)row * DD);
    const f4* vh = (const f4*)v;
    const f4* vm = (const f4*)(v + DD);

    float ah = 0.f, am = 0.f;
    #pragma unroll
    for (int k = 0; k < 4; ++k) {
        int idx = lane + 64 * k;
        f4 xv = __builtin_nontemporal_load(xr + idx);
        f4 hv = vh[idx];
        f4 mv = vm[idx];
        ah += xv.x*hv.x + xv.y*hv.y + xv.z*hv.z + xv.w*hv.w;
        am += xv.x*mv.x + xv.y*mv.y + xv.z*mv.z + xv.w*mv.w;
    }
    #pragma unroll
    for (int off = 32; off > 0; off >>= 1) {
        ah += __shfl_down(ah, off, 64);
        am += __shfl_down(am, off, 64);
    }
    if (lane == 0) {
        sH[row] = ah + *Cc;
        sM[row] = am;
    }
}

// ---------------------------------------------------------------------------
// Kernel C (2048 blocks x 256): out[b,i,j] = sH[b*N+i] + sM[b*N+j]
// Each block: 8 consecutive rows of one batch. Thread's sM float4 loaded ONCE,
// reused across 8 rows; output stored nontemporally (pure 64 MiB stream, no
// L2 allocation churn).
// ---------------------------------------------------------------------------
__global__ __launch_bounds__(256) void scores_kernel(
    const float* __restrict__ sH, const float* __restrict__ sM,
    f4* __restrict__ out) {
    const int bi0 = blockIdx.x * 8;                  // first row (b*N+i)
    const int b = bi0 >> 10;
    const int j4 = threadIdx.x;                      // float4 index in row
    const f4 mv = ((const f4*)(sM + b * NN))[j4];
    #pragma unroll
    for (int it = 0; it < 8; ++it) {
        const int bi = bi0 + it;
        const float h = sH[bi];
        f4 o = { h + mv.x, h + mv.y, h + mv.z, h + mv.w };
        __builtin_nontemporal_store(o, out + (size_t)bi * (NN / 4) + j4);
    }
}

extern "C" void kernel_launch(void* const* d_in, const int* in_sizes, int n_in,
                              void* d_out, int out_size, void* d_ws, size_t ws_size,
                              hipStream_t stream) {
    const float* x     = (const float*)d_in[0];
    const float* W_h   = (const float*)d_in[1];
    const float* b_h   = (const float*)d_in[2];
    const float* W_m   = (const float*)d_in[3];
    const float* b_m   = (const float*)d_in[4];
    const float* w_out = (const float*)d_in[5];
    const float* b_out = (const float*)d_in[6];
    float* out = (float*)d_out;

    float* ws = (float*)d_ws;
    float* v  = ws;               // 2048 (v_h | v_m)
    float* Cc = ws + 2048;        // 1
    float* sH = ws + 4096;        // 16384
    float* sM = ws + 4096 + 16384;

    prep_kernel<<<17, 1024, 0, stream>>>(W_h, W_m, b_h, b_m, w_out, b_out, v, Cc);
    row_dots_kernel<<<BB * NN / 4, 256, 0, stream>>>(x, v, Cc, sH, sM);
    scores_kernel<<<BB * NN / 8, 256, 0, stream>>>(sH, sM, (f4*)out);
}

// Round 7
// 127.644 us; speedup vs baseline: 1.0712x; 1.0712x over previous
//
#include <hip/hip_runtime.h>

// Problem constants (match reference): B=16, N=1024, D2H=1024, U=512
#define BB 16
#define NN 1024
#define DD 1024
#define UU 512

// ---------------------------------------------------------------------------
// Kernel A (17 blocks x 1024): deterministic, no atomics, no memset.
// blocks 0..15: v[m*DD + d] = sum_u W[u,d] * w_out[u]  (m=0: W_h, m=1: W_m)
// block 16: C = (b_h+b_m)·w_out + b_out
// ---------------------------------------------------------------------------
__global__ __launch_bounds__(1024) void prep_kernel(
    const float* __restrict__ W_h, const float* __restrict__ W_m,
    const float* __restrict__ b_h, const float* __restrict__ b_m,
    const float* __restrict__ w_out, const float* __restrict__ b_out,
    float* __restrict__ v, float* __restrict__ Cc) {
    const int t = threadIdx.x;
    const int blk = blockIdx.x;
    if (blk < 16) {
        __shared__ float red[8][128];
        const int m = blk >> 3;              // 0 -> W_h, 1 -> W_m
        const int d0 = (blk & 7) * 128;      // d-chunk
        const float* W = m ? W_m : W_h;
        const int dl = t & 127;              // d within chunk
        const int p = t >> 7;                // u-chunk 0..7 (64 u each)
        const float* Wp = W + (size_t)(p * 64) * DD + d0 + dl;
        float acc = 0.f;
        #pragma unroll
        for (int k = 0; k < 64; ++k)
            acc += Wp[(size_t)k * DD] * w_out[p * 64 + k];
        red[p][dl] = acc;
        __syncthreads();
        if (t < 128) {
            float s = 0.f;
            #pragma unroll
            for (int q = 0; q < 8; ++q) s += red[q][t];
            v[m * DD + d0 + t] = s;
        }
    } else {
        __shared__ float r2[512];
        float acc = 0.f;
        if (t < UU) acc = (b_h[t] + b_m[t]) * w_out[t];
        if (t < 512) r2[t] = acc;
        __syncthreads();
        for (int s = 256; s > 0; s >>= 1) {
            if (t < s) r2[t] += r2[t + s];
            __syncthreads();
        }
        if (t == 0) *Cc = r2[0] + b_out[0];
    }
}

// ---------------------------------------------------------------------------
// Kernel B: sH[row] = x[row]·v_h + C ; sM[row] = x[row]·v_m   (row = b*N+n)
// One wave per row, 4 waves/block. v (8 KB) is L1-hot; x read exactly once.
// ---------------------------------------------------------------------------
__global__ __launch_bounds__(256) void row_dots_kernel(
    const float* __restrict__ x, const float* __restrict__ v,
    const float* __restrict__ Cc,
    float* __restrict__ sH, float* __restrict__ sM) {
    const int t = threadIdx.x;
    const int wave = t >> 6, lane = t & 63;
    const int row = blockIdx.x * 4 + wave;           // [0, B*N)
    const float4* xr = (const float4*)(x + (size_t)row * DD);
    const float4* vh = (const float4*)v;
    const float4* vm = (const float4*)(v + DD);

    float ah = 0.f, am = 0.f;
    #pragma unroll
    for (int k = 0; k < 4; ++k) {
        int idx = lane + 64 * k;
        float4 xv = xr[idx];
        float4 hv = vh[idx];
        float4 mv = vm[idx];
        ah += xv.x*hv.x + xv.y*hv.y + xv.z*hv.z + xv.w*hv.w;
        am += xv.x*mv.x + xv.y*mv.y + xv.z*mv.z + xv.w*mv.w;
    }
    #pragma unroll
    for (int off = 32; off > 0; off >>= 1) {
        ah += __shfl_down(ah, off, 64);
        am += __shfl_down(am, off, 64);
    }
    if (lane == 0) {
        sH[row] = ah + *Cc;
        sM[row] = am;
    }
}

// ---------------------------------------------------------------------------
// Kernel C (4096 blocks x 256): out[b,i,j] = sH[b*N+i] + sM[b*N+j]
// Each block: 4 consecutive rows of one batch. Thread's sM float4 loaded ONCE,
// reused across the 4 rows; sH is a block-uniform scalar load per row.
// Stores: 1 KB contiguous per wave per row — pure streaming.
// ---------------------------------------------------------------------------
__global__ __launch_bounds__(256) void scores_kernel(
    const float* __restrict__ sH, const float* __restrict__ sM,
    float4* __restrict__ out) {
    const int bi0 = blockIdx.x * 4;                  // first row (b*N+i)
    const int b = bi0 >> 10;
    const int j4 = threadIdx.x;                      // float4 index in row
    const float4 mv = ((const float4*)(sM + b * NN))[j4];
    #pragma unroll
    for (int it = 0; it < 4; ++it) {
        const int bi = bi0 + it;
        const float h = sH[bi];
        float4 o = { h + mv.x, h + mv.y, h + mv.z, h + mv.w };
        out[(size_t)bi * (NN / 4) + j4] = o;
    }
}

extern "C" void kernel_launch(void* const* d_in, const int* in_sizes, int n_in,
                              void* d_out, int out_size, void* d_ws, size_t ws_size,
                              hipStream_t stream) {
    const float* x     = (const float*)d_in[0];
    const float* W_h   = (const float*)d_in[1];
    const float* b_h   = (const float*)d_in[2];
    const float* W_m   = (const float*)d_in[3];
    const float* b_m   = (const float*)d_in[4];
    const float* w_out = (const float*)d_in[5];
    const float* b_out = (const float*)d_in[6];
    float* out = (float*)d_out;

    float* ws = (float*)d_ws;
    float* v  = ws;               // 2048 (v_h | v_m)
    float* Cc = ws + 2048;        // 1
    float* sH = ws + 4096;        // 16384
    float* sM = ws + 4096 + 16384;

    prep_kernel<<<17, 1024, 0, stream>>>(W_h, W_m, b_h, b_m, w_out, b_out, v, Cc);
    row_dots_kernel<<<BB * NN / 4, 256, 0, stream>>>(x, v, Cc, sH, sM);
    scores_kernel<<<BB * NN / 4, 256, 0, stream>>>(sH, sM, (float4*)out);
}